// Round 10
// baseline (219.433 us; speedup 1.0000x reference)
//
#include <hip/hip_runtime.h>
#include <hip/hip_bf16.h>

// Problem constants
#define BB 32
#define SS 1024
#define TT 64
#define HD 1024   // 2H
#define FF 2048   // 4H
#define MM (BB*SS) // 32768

typedef __attribute__((ext_vector_type(4))) float f32x4;
typedef __attribute__((ext_vector_type(8))) short bf16x8;
typedef __attribute__((ext_vector_type(8))) unsigned short u16x8;

__device__ __forceinline__ unsigned short f2bf(float f) {
  __hip_bfloat16 h = __float2bfloat16(f);
  return __builtin_bit_cast(unsigned short, h);
}

__device__ __forceinline__ void gll16(const void* g, void* l) {
  __builtin_amdgcn_global_load_lds(
      (const __attribute__((address_space(1))) void*)g,
      (__attribute__((address_space(3))) void*)l, 16, 0, 0);
}

// ---------------------------------------------------------------- prep
// blocks [0,2048): transpose+convert W fp32 [2048][1024] -> Wt bf16 [1024][2048]
// blocks [2048,2176): convert tgt fp32 -> bf16 (grid-stride float4)
__global__ __launch_bounds__(256) void prep_kernel(
    const float* __restrict__ W, unsigned short* __restrict__ Wt_bf,
    const float* __restrict__ tgt, unsigned short* __restrict__ tgt_bf) {
  __shared__ float tile[32][33];
  const int gb = blockIdx.x;
  const int tid = threadIdx.x;
  if (gb < 2048) {
    const int bx = gb & 31, by = gb >> 5;       // (HD/32=32) x (FF/32=64)
    const int c0 = bx * 32, r0 = by * 32;
    const int tx = tid & 31, ty = tid >> 5;     // (32, 8)
#pragma unroll
    for (int j = 0; j < 4; ++j)
      tile[ty + j * 8][tx] = W[(size_t)(r0 + ty + j * 8) * HD + c0 + tx];
    __syncthreads();
#pragma unroll
    for (int j = 0; j < 4; ++j)
      Wt_bf[(size_t)(c0 + ty + j * 8) * FF + r0 + tx] = f2bf(tile[tx][ty + j * 8]);
  } else {
    const int n4 = (BB * TT * HD) / 4;
    for (int i = (gb - 2048) * 256 + tid; i < n4; i += 128 * 256) {
      float4 v = reinterpret_cast<const float4*>(tgt)[i];
      ushort4 o;
      o.x = f2bf(v.x); o.y = f2bf(v.y); o.z = f2bf(v.z); o.w = f2bf(v.w);
      reinterpret_cast<ushort4*>(tgt_bf)[i] = o;
    }
  }
}

// ---------------------------------------------------------------- U = tgt @ W2
// Ut[b][d][t] bf16 (transposed) so the main gemm stages it as stride-64 B-tile.
__global__ __launch_bounds__(256) void u_kernel(
    const unsigned short* __restrict__ tgt_bf,  // [B][T][1024]
    const unsigned short* __restrict__ Wt_bf,   // [1024 d][2048 f]
    unsigned short* __restrict__ Ut)            // [B][1024 d][64 t]
{
  const int tid = threadIdx.x;
  const int w = tid >> 6, l = tid & 63;
  const int lrow = l & 15, lk = l >> 4;
  const int nb = blockIdx.x * 64;   // d base
  const int b = blockIdx.y;

  const unsigned short* ap = tgt_bf + (size_t)b * TT * HD
                             + (size_t)(w * 16 + lrow) * HD + lk * 8;
  const unsigned short* wp = Wt_bf + (size_t)(nb + lrow) * FF + 1024 + lk * 8;

  f32x4 acc[4] = {};
#pragma unroll 2
  for (int kt = 0; kt < 32; ++kt) {
    const int kk = kt * 32;
    bf16x8 a = *reinterpret_cast<const bf16x8*>(ap + kk);
#pragma unroll
    for (int ct = 0; ct < 4; ++ct) {
      bf16x8 bb = *reinterpret_cast<const bf16x8*>(wp + (size_t)ct * 16 * FF + kk);
      acc[ct] = __builtin_amdgcn_mfma_f32_16x16x32_bf16(a, bb, acc[ct], 0, 0, 0);
    }
  }
  unsigned short* up = Ut + (size_t)b * HD * TT;
#pragma unroll
  for (int ct = 0; ct < 4; ++ct)
#pragma unroll
    for (int j = 0; j < 4; ++j)
      up[(size_t)(nb + ct * 16 + lrow) * TT + (w * 16 + lk * 4 + j)] = f2bf(acc[ct][j]);
}

// ---------------------------------------------------------------- attention
// QK^T + softmax (PV folded into gemm via P@(tgt.W2)). Barrier-free, no LDS.
// R10: 2-deep software pipeline — loads for kt+1 issued before kt's MFMAs
// (6 vmem ops in flight), hiding HBM latency at 2-waves/SIMD occupancy.
__global__ __launch_bounds__(256) void attn_kernel(
    const float* __restrict__ hid_f32,           // [B][S][D] fp32
    unsigned short* __restrict__ hid_bf,         // out: [B][S][D] bf16
    const unsigned short* __restrict__ tgt_bf,   // [B][T][D]
    unsigned short* __restrict__ P_bf)           // out: [M][64]
{
  const int tid = threadIdx.x;
  const int w = tid >> 6, l = tid & 63;
  const int lrow = l & 15, lk = l >> 4;
  const int b = blockIdx.y;
  const int sbase = blockIdx.x * 64;
  const size_t hbase = ((size_t)b * SS + sbase) * HD;

  const int qrow = w * 16 + lrow;
  const float* qp = hid_f32 + hbase + (size_t)qrow * HD + lk * 8;
  unsigned short* qbf = hid_bf + hbase + (size_t)qrow * HD + lk * 8;
  const unsigned short* kp = tgt_bf + (size_t)b * TT * HD + (size_t)lrow * HD + lk * 8;

  f32x4 accs[4] = {};
  float4 f0A, f1A, f0B, f1B;
  bf16x8 kfA[4], kfB[4];

  f0A = *reinterpret_cast<const float4*>(qp);
  f1A = *reinterpret_cast<const float4*>(qp + 4);
#pragma unroll
  for (int ct = 0; ct < 4; ++ct)
    kfA[ct] = *reinterpret_cast<const bf16x8*>(kp + (size_t)ct * 16 * HD);

  for (int kt = 0; kt < 32; kt += 2) {
    const int kkB = kt * 32 + 32;
    // issue B(kt+1) loads
    f0B = *reinterpret_cast<const float4*>(qp + kkB);
    f1B = *reinterpret_cast<const float4*>(qp + kkB + 4);
#pragma unroll
    for (int ct = 0; ct < 4; ++ct)
      kfB[ct] = *reinterpret_cast<const bf16x8*>(kp + (size_t)ct * 16 * HD + kkB);
    // compute A(kt)
    bf16x8 a;
    a[0] = (short)f2bf(f0A.x); a[1] = (short)f2bf(f0A.y);
    a[2] = (short)f2bf(f0A.z); a[3] = (short)f2bf(f0A.w);
    a[4] = (short)f2bf(f1A.x); a[5] = (short)f2bf(f1A.y);
    a[6] = (short)f2bf(f1A.z); a[7] = (short)f2bf(f1A.w);
    *reinterpret_cast<bf16x8*>(qbf + kt * 32) = a;
#pragma unroll
    for (int ct = 0; ct < 4; ++ct)
      accs[ct] = __builtin_amdgcn_mfma_f32_16x16x32_bf16(a, kfA[ct], accs[ct], 0, 0, 0);
    // issue A(kt+2) loads
    if (kt + 2 < 32) {
      const int kkA = kt * 32 + 64;
      f0A = *reinterpret_cast<const float4*>(qp + kkA);
      f1A = *reinterpret_cast<const float4*>(qp + kkA + 4);
#pragma unroll
      for (int ct = 0; ct < 4; ++ct)
        kfA[ct] = *reinterpret_cast<const bf16x8*>(kp + (size_t)ct * 16 * HD + kkA);
    }
    // compute B(kt+1)
    bf16x8 bb;
    bb[0] = (short)f2bf(f0B.x); bb[1] = (short)f2bf(f0B.y);
    bb[2] = (short)f2bf(f0B.z); bb[3] = (short)f2bf(f0B.w);
    bb[4] = (short)f2bf(f1B.x); bb[5] = (short)f2bf(f1B.y);
    bb[6] = (short)f2bf(f1B.z); bb[7] = (short)f2bf(f1B.w);
    *reinterpret_cast<bf16x8*>(qbf + kkB) = bb;
#pragma unroll
    for (int ct = 0; ct < 4; ++ct)
      accs[ct] = __builtin_amdgcn_mfma_f32_16x16x32_bf16(bb, kfB[ct], accs[ct], 0, 0, 0);
  }

  // softmax over t (lane holds q-rows lk*4+j, t-cols ct*16+lrow)
  float p[4][4];
#pragma unroll
  for (int j = 0; j < 4; ++j) {
    float mx = fmaxf(fmaxf(accs[0][j], accs[1][j]), fmaxf(accs[2][j], accs[3][j]));
#pragma unroll
    for (int d = 1; d < 16; d <<= 1) mx = fmaxf(mx, __shfl_xor(mx, d, 64));
    float sum = 0.f;
#pragma unroll
    for (int ct = 0; ct < 4; ++ct) { p[ct][j] = __expf(accs[ct][j] - mx); sum += p[ct][j]; }
#pragma unroll
    for (int d = 1; d < 16; d <<= 1) sum += __shfl_xor(sum, d, 64);
    float inv = 1.f / sum;
#pragma unroll
    for (int ct = 0; ct < 4; ++ct) p[ct][j] *= inv;
  }
#pragma unroll
  for (int j = 0; j < 4; ++j) {
    const size_t prow = ((size_t)b * SS + sbase + w * 16 + lk * 4 + j) * TT;
#pragma unroll
    for (int ct = 0; ct < 4; ++ct)
      P_bf[prow + ct * 16 + lrow] = f2bf(p[ct][j]);
  }
}

// ---------------------------------------------------------------- transform GEMM
// out = tanh(hid.W1 + P.U + b) + hid.  K = 1024 (hid x W1) + 64 (P x Ut[b]).
// R9 measured: 104.5us, 0 conflicts. Unchanged this round.

__global__ __launch_bounds__(512) void gemm_kernel(
    const unsigned short* __restrict__ hid_bf,  // [M][1024]
    const unsigned short* __restrict__ P_bf,    // [M][64]
    const unsigned short* __restrict__ Wt_bf,   // [1024][2048]  (n-major)
    const unsigned short* __restrict__ Ut,      // [B][1024][64]
    const float* __restrict__ bias,             // [1024]
    float* __restrict__ out)                    // [M][1024]
{
  __shared__ unsigned short lds[65536];  // 128 KiB

  const int tid = threadIdx.x;
  const int w = tid >> 6, l = tid & 63;
  const int wm = w >> 2, wn = w & 3;       // 2 x 4 wave grid
  const int lrow = l & 15, lk = l >> 4;

  // XCD-aware bijective swizzle (nwg = 512, divisible by 8)
  const int orig = blockIdx.y * 4 + blockIdx.x;
  const int lid = (orig & 7) * 64 + (orig >> 3);
  const int nbase = (lid & 3) * 256;
  const int mbase = (lid >> 2) * 256;
  const int bidx = mbase >> 10;            // batch of this block's rows

  const int srow8 = w * 8 + (l >> 3);           // 0..63
  const int scol = ((l & 7) ^ (l >> 3)) << 3;   // pre-swizzled col chunk

  const int ck0 = ((lk)     ^ (lrow & 7)) << 3;
  const int ck1 = ((4 + lk) ^ (lrow & 7)) << 3;

#define STAGE_A(s, bsel, h) do {                                               \
    const unsigned short* p_; size_t str_;                                     \
    if ((s) < 16) { p_ = hid_bf + (s) * 64; str_ = 1024; }                     \
    else          { p_ = P_bf;              str_ = 64;   }                     \
    _Pragma("unroll")                                                          \
    for (int rd_ = 0; rd_ < 2; ++rd_)                                          \
      gll16(p_ + (size_t)(mbase + (h) * 128 + rd_ * 64 + srow8) * str_ + scol, \
            lds + (bsel) * 32768 + (h) * 8192 + rd_ * 4096 + w * 512);         \
  } while (0)

#define STAGE_B(s, bsel, h) do {                                               \
    const unsigned short* p_; size_t str_;                                     \
    if ((s) < 16) { p_ = Wt_bf + (s) * 64;               str_ = 2048; }        \
    else          { p_ = Ut + (size_t)bidx * HD * TT;    str_ = 64;   }        \
    _Pragma("unroll")                                                          \
    for (int rd_ = 0; rd_ < 2; ++rd_)                                          \
      gll16(p_ + (size_t)(nbase + (h) * 128 + rd_ * 64 + srow8) * str_ + scol, \
            lds + (bsel) * 32768 + 16384 + (h) * 8192 + rd_ * 4096 + w * 512); \
  } while (0)

#define PH_MID do { __builtin_amdgcn_s_setprio(1); } while (0)
#define PH_END do {                                                            \
    __builtin_amdgcn_s_setprio(0);                                             \
    __builtin_amdgcn_sched_barrier(0);                                         \
    __builtin_amdgcn_s_barrier();                                              \
  } while (0)

  f32x4 acc[8][4] = {};
  bf16x8 aR[4][2], bR[4][2];

  // prologue: A0,A1,B0,B1(tile0); B0,B1(tile1). vmcnt(4) -> tile0 landed.
  STAGE_A(0, 0, 0); STAGE_A(0, 0, 1);
  STAGE_B(0, 0, 0); STAGE_B(0, 0, 1);
  STAGE_B(1, 1, 0); STAGE_B(1, 1, 1);
  asm volatile("s_waitcnt vmcnt(4)" ::: "memory");
  __builtin_amdgcn_sched_barrier(0);
  __builtin_amdgcn_s_barrier();

#define TILE(tt, c, last) do {                                                 \
    const int sa_ = ((tt) + 1 > 16) ? 16 : (tt) + 1;                           \
    const int sb_ = ((tt) + 2 > 16) ? 16 : (tt) + 2;                           \
    const int abase_ = (c) * 32768 + wm * 8192 + lrow * 64;                    \
    const int bbase_ = (c) * 32768 + 16384 + (wn >> 1) * 8192                  \
                       + ((wn & 1) * 64 + lrow) * 64;                          \
    /* ---- P0: a[0..3], b[0..1]; stage A0(sa); MFMA m0-3 x n0-1 ---- */       \
    _Pragma("unroll")                                                          \
    for (int m_ = 0; m_ < 4; ++m_) {                                           \
      aR[m_][0] = *(const bf16x8*)(lds + abase_ + m_ * 1024 + ck0);            \
      aR[m_][1] = *(const bf16x8*)(lds + abase_ + m_ * 1024 + ck1);            \
    }                                                                          \
    _Pragma("unroll")                                                          \
    for (int n_ = 0; n_ < 2; ++n_) {                                           \
      bR[n_][0] = *(const bf16x8*)(lds + bbase_ + n_ * 1024 + ck0);            \
      bR[n_][1] = *(const bf16x8*)(lds + bbase_ + n_ * 1024 + ck1);            \
    }                                                                          \
    STAGE_A(sa_, 1 - (c), 0);                                                  \
    PH_MID;                                                                    \
    _Pragma("unroll")                                                          \
    for (int m_ = 0; m_ < 4; ++m_)                                             \
      _Pragma("unroll")                                                        \
      for (int n_ = 0; n_ < 2; ++n_) {                                         \
        acc[m_][n_] = __builtin_amdgcn_mfma_f32_16x16x32_bf16(                 \
            aR[m_][0], bR[n_][0], acc[m_][n_], 0, 0, 0);                       \
        acc[m_][n_] = __builtin_amdgcn_mfma_f32_16x16x32_bf16(                 \
            aR[m_][1], bR[n_][1], acc[m_][n_], 0, 0, 0);                       \
      }                                                                        \
    PH_END;                                                                    \
    /* ---- P1: b[2..3]; stage A1(sa); MFMA m0-3 x n2-3 ---- */                \
    _Pragma("unroll")                                                          \
    for (int n_ = 2; n_ < 4; ++n_) {                                           \
      bR[n_][0] = *(const bf16x8*)(lds + bbase_ + n_ * 1024 + ck0);            \
      bR[n_][1] = *(const bf16x8*)(lds + bbase_ + n_ * 1024 + ck1);            \
    }                                                                          \
    STAGE_A(sa_, 1 - (c), 1);                                                  \
    PH_MID;                                                                    \
    _Pragma("unroll")                                                          \
    for (int m_ = 0; m_ < 4; ++m_)                                             \
      _Pragma("unroll")                                                        \
      for (int n_ = 2; n_ < 4; ++n_) {                                         \
        acc[m_][n_] = __builtin_amdgcn_mfma_f32_16x16x32_bf16(                 \
            aR[m_][0], bR[n_][0], acc[m_][n_], 0, 0, 0);                       \
        acc[m_][n_] = __builtin_amdgcn_mfma_f32_16x16x32_bf16(                 \
            aR[m_][1], bR[n_][1], acc[m_][n_], 0, 0, 0);                       \
      }                                                                        \
    PH_END;                                                                    \
    /* ---- P2: a[4..7]; stage B0(sb); MFMA m4-7 x n0-1 ---- */                \
    _Pragma("unroll")                                                          \
    for (int m_ = 0; m_ < 4; ++m_) {                                           \
      aR[m_][0] = *(const bf16x8*)(lds + abase_ + (m_ + 4) * 1024 + ck0);      \
      aR[m_][1] = *(const bf16x8*)(lds + abase_ + (m_ + 4) * 1024 + ck1);      \
    }                                                                          \
    STAGE_B(sb_, (c), 0);                                                      \
    PH_MID;                                                                    \
    _Pragma("unroll")                                                          \
    for (int m_ = 0; m_ < 4; ++m_)                                             \
      _Pragma("unroll")                                                        \
      for (int n_ = 0; n_ < 2; ++n_) {                                         \
        acc[m_ + 4][n_] = __builtin_amdgcn_mfma_f32_16x16x32_bf16(             \
            aR[m_][0], bR[n_][0], acc[m_ + 4][n_], 0, 0, 0);                   \
        acc[m_ + 4][n_] = __builtin_amdgcn_mfma_f32_16x16x32_bf16(             \
            aR[m_][1], bR[n_][1], acc[m_ + 4][n_], 0, 0, 0);                   \
      }                                                                        \
    PH_END;                                                                    \
    /* ---- P3: stage B1(sb); MFMA m4-7 x n2-3; vmcnt ---- */                  \
    STAGE_B(sb_, (c), 1);                                                      \
    PH_MID;                                                                    \
    _Pragma("unroll")                                                          \
    for (int m_ = 0; m_ < 4; ++m_)                                             \
      _Pragma("unroll")                                                        \
      for (int n_ = 2; n_ < 4; ++n_) {                                         \
        acc[m_ + 4][n_] = __builtin_amdgcn_mfma_f32_16x16x32_bf16(             \
            aR[m_][0], bR[n_][0], acc[m_ + 4][n_], 0, 0, 0);                   \
        acc[m_ + 4][n_] = __builtin_amdgcn_mfma_f32_16x16x32_bf16(             \
            aR[m_][1], bR[n_][1], acc[m_ + 4][n_], 0, 0, 0);                   \
      }                                                                        \
    __builtin_amdgcn_s_setprio(0);                                             \
    if (last) { asm volatile("s_waitcnt vmcnt(0)" ::: "memory"); }             \
    else      { asm volatile("s_waitcnt vmcnt(4)" ::: "memory"); }             \
    __builtin_amdgcn_sched_barrier(0);                                         \
    __builtin_amdgcn_s_barrier();                                              \
  } while (0)

  for (int tt = 0; tt < 16; tt += 2) {
    TILE(tt, 0, false);
    TILE(tt + 1, 1, false);
  }
  TILE(16, 0, true);   // P x Ut[b] tile (dead stages keep vmcnt uniform)
#undef TILE
#undef PH_MID
#undef PH_END
#undef STAGE_A
#undef STAGE_B

  // epilogue: tanh + bias + bf16 residual (hid_bf L2-warm from staging)
#pragma unroll
  for (int m = 0; m < 8; ++m) {
    const int row = mbase + wm * 128 + m * 16 + lk * 4;
#pragma unroll
    for (int n = 0; n < 4; ++n) {
      const int col = nbase + wn * 64 + n * 16 + lrow;
      const float bv = bias[col];
#pragma unroll
      for (int j = 0; j < 4; ++j) {
        float x = acc[m][n][j] + bv;
        float xc = fminf(fmaxf(x, -15.f), 15.f);
        float e2 = __expf(2.f * xc);
        float th = (e2 - 1.f) / (e2 + 1.f);
        size_t oi = (size_t)(row + j) * HD + col;
        unsigned int u = ((unsigned int)hid_bf[oi]) << 16;
        out[oi] = th + __builtin_bit_cast(float, u);
      }
    }
  }
}

// ---------------------------------------------------------------- launch
extern "C" void kernel_launch(void* const* d_in, const int* in_sizes, int n_in,
                              void* d_out, int out_size, void* d_ws, size_t ws_size,
                              hipStream_t stream) {
  const float* tgt  = (const float*)d_in[0];  // (B,T,2H)
  const float* hid  = (const float*)d_in[1];  // (B,S,2H)
  const float* W    = (const float*)d_in[2];  // (4H,2H)
  const float* bias = (const float*)d_in[3];  // (2H,)
  float* out = (float*)d_out;

  char* ws = (char*)d_ws;
  unsigned short* hid_bf = (unsigned short*)(ws);                //  64 MiB
  unsigned short* tgt_bf = (unsigned short*)(ws + 67108864);     //   4 MiB
  unsigned short* Wt_bf  = (unsigned short*)(ws + 71303168);     //   4 MiB
  unsigned short* P_bf   = (unsigned short*)(ws + 75497472);     //   4 MiB
  unsigned short* Ut     = (unsigned short*)(ws + 79691776);     //   4 MiB

  prep_kernel<<<2176, 256, 0, stream>>>(W, Wt_bf, tgt, tgt_bf);
  u_kernel<<<dim3(HD / 64, BB), 256, 0, stream>>>(tgt_bf, Wt_bf, Ut);
  attn_kernel<<<dim3(SS / 64, BB), 256, 0, stream>>>(hid, hid_bf, tgt_bf, P_bf);
  gemm_kernel<<<dim3(HD / 128 / 2, MM / 256), 512, 0, stream>>>(hid_bf, P_bf, Wt_bf, Ut, bias, out);
}

// Round 11
// 217.425 us; speedup vs baseline: 1.0092x; 1.0092x over previous
//
#include <hip/hip_runtime.h>
#include <hip/hip_bf16.h>

// Problem constants
#define BB 32
#define SS 1024
#define TT 64
#define HD 1024   // 2H
#define FF 2048   // 4H
#define MM (BB*SS) // 32768

typedef __attribute__((ext_vector_type(4))) float f32x4;
typedef __attribute__((ext_vector_type(8))) short bf16x8;
typedef __attribute__((ext_vector_type(8))) unsigned short u16x8;

__device__ __forceinline__ unsigned short f2bf(float f) {
  __hip_bfloat16 h = __float2bfloat16(f);
  return __builtin_bit_cast(unsigned short, h);
}

__device__ __forceinline__ void gll16(const void* g, void* l) {
  __builtin_amdgcn_global_load_lds(
      (const __attribute__((address_space(1))) void*)g,
      (__attribute__((address_space(3))) void*)l, 16, 0, 0);
}

// ---------------------------------------------------------------- converts
__global__ void cvt_bf16_kernel(const float* __restrict__ x,
                                unsigned short* __restrict__ y, int n4) {
  int stride = gridDim.x * blockDim.x;
  for (int i = blockIdx.x * blockDim.x + threadIdx.x; i < n4; i += stride) {
    float4 v = reinterpret_cast<const float4*>(x)[i];
    ushort4 o;
    o.x = f2bf(v.x); o.y = f2bf(v.y); o.z = f2bf(v.z); o.w = f2bf(v.w);
    reinterpret_cast<ushort4*>(y)[i] = o;
  }
}

// transpose+convert: in fp32 [R][C] -> out bf16 [C][R]   (W: 2048x1024 -> 1024x2048)
__global__ void tcvt_kernel(const float* __restrict__ in,
                            unsigned short* __restrict__ out, int R, int C) {
  __shared__ float tile[32][33];
  const int c0 = blockIdx.x * 32, r0 = blockIdx.y * 32;
  const int tx = threadIdx.x, ty = threadIdx.y; // (32, 8)
#pragma unroll
  for (int j = 0; j < 4; ++j)
    tile[ty + j * 8][tx] = in[(size_t)(r0 + ty + j * 8) * C + c0 + tx];
  __syncthreads();
#pragma unroll
  for (int j = 0; j < 4; ++j)
    out[(size_t)(c0 + ty + j * 8) * R + r0 + tx] = f2bf(tile[tx][ty + j * 8]);
}

// ---------------------------------------------------------------- U = tgt @ W2
// Ut[b][d][t] bf16 (transposed) so the main gemm stages it as stride-64 B-tile.
__global__ __launch_bounds__(256) void u_kernel(
    const unsigned short* __restrict__ tgt_bf,  // [B][T][1024]
    const unsigned short* __restrict__ Wt_bf,   // [1024 d][2048 f]
    unsigned short* __restrict__ Ut)            // [B][1024 d][64 t]
{
  const int tid = threadIdx.x;
  const int w = tid >> 6, l = tid & 63;
  const int lrow = l & 15, lk = l >> 4;
  const int nb = blockIdx.x * 64;   // d base
  const int b = blockIdx.y;

  const unsigned short* ap = tgt_bf + (size_t)b * TT * HD
                             + (size_t)(w * 16 + lrow) * HD + lk * 8;
  const unsigned short* wp = Wt_bf + (size_t)(nb + lrow) * FF + 1024 + lk * 8;

  f32x4 acc[4] = {};
  for (int kt = 0; kt < 32; ++kt) {
    const int kk = kt * 32;
    bf16x8 a = *reinterpret_cast<const bf16x8*>(ap + kk);
#pragma unroll
    for (int ct = 0; ct < 4; ++ct) {
      bf16x8 bb = *reinterpret_cast<const bf16x8*>(wp + (size_t)ct * 16 * FF + kk);
      acc[ct] = __builtin_amdgcn_mfma_f32_16x16x32_bf16(a, bb, acc[ct], 0, 0, 0);
    }
  }
  unsigned short* up = Ut + (size_t)b * HD * TT;
#pragma unroll
  for (int ct = 0; ct < 4; ++ct)
#pragma unroll
    for (int j = 0; j < 4; ++j)
      up[(size_t)(nb + ct * 16 + lrow) * TT + (w * 16 + lk * 4 + j)] = f2bf(acc[ct][j]);
}

// ---------------------------------------------------------------- attention
// R11: QK^T + softmax reading hid_bf (bf16, pre-converted; L3-resident).
// Loop body = 1 A-load + 4 L2 K-loads + 4 MFMA. No cvt chain, no stores,
// no barriers, no LDS. P bf16 out (4 MB).
__global__ __launch_bounds__(256) void attn_kernel(
    const unsigned short* __restrict__ hid_bf,   // [B][S][D] bf16
    const unsigned short* __restrict__ tgt_bf,   // [B][T][D]
    unsigned short* __restrict__ P_bf)           // out: [M][64]
{
  const int tid = threadIdx.x;
  const int w = tid >> 6, l = tid & 63;
  const int lrow = l & 15, lk = l >> 4;
  const int b = blockIdx.y;
  const int sbase = blockIdx.x * 64;
  const size_t hbase = ((size_t)b * SS + sbase) * HD;

  const int qrow = w * 16 + lrow;
  const unsigned short* qp = hid_bf + hbase + (size_t)qrow * HD + lk * 8;
  const unsigned short* kp = tgt_bf + (size_t)b * TT * HD + (size_t)lrow * HD + lk * 8;

  f32x4 accs[4] = {};
#pragma unroll 2
  for (int kt = 0; kt < 32; ++kt) {
    const int kk = kt * 32;
    bf16x8 a = *reinterpret_cast<const bf16x8*>(qp + kk);
#pragma unroll
    for (int ct = 0; ct < 4; ++ct) {
      bf16x8 bb = *reinterpret_cast<const bf16x8*>(kp + (size_t)ct * 16 * HD + kk);
      accs[ct] = __builtin_amdgcn_mfma_f32_16x16x32_bf16(a, bb, accs[ct], 0, 0, 0);
    }
  }

  // softmax over t (lane holds q-rows lk*4+j, t-cols ct*16+lrow)
  float p[4][4];
#pragma unroll
  for (int j = 0; j < 4; ++j) {
    float mx = fmaxf(fmaxf(accs[0][j], accs[1][j]), fmaxf(accs[2][j], accs[3][j]));
#pragma unroll
    for (int d = 1; d < 16; d <<= 1) mx = fmaxf(mx, __shfl_xor(mx, d, 64));
    float sum = 0.f;
#pragma unroll
    for (int ct = 0; ct < 4; ++ct) { p[ct][j] = __expf(accs[ct][j] - mx); sum += p[ct][j]; }
#pragma unroll
    for (int d = 1; d < 16; d <<= 1) sum += __shfl_xor(sum, d, 64);
    float inv = 1.f / sum;
#pragma unroll
    for (int ct = 0; ct < 4; ++ct) p[ct][j] *= inv;
  }
#pragma unroll
  for (int j = 0; j < 4; ++j) {
    const size_t prow = ((size_t)b * SS + sbase + w * 16 + lk * 4 + j) * TT;
#pragma unroll
    for (int ct = 0; ct < 4; ++ct)
      P_bf[prow + ct * 16 + lrow] = f2bf(p[ct][j]);
  }
}

// ---------------------------------------------------------------- transform GEMM
// out = tanh(hid.W1 + P.U + b) + hid.  K = 1024 (hid x W1) + 64 (P x Ut[b]).
// R9 measured: 104.5us, 0 conflicts. Unchanged.

__global__ __launch_bounds__(512) void gemm_kernel(
    const unsigned short* __restrict__ hid_bf,  // [M][1024]
    const unsigned short* __restrict__ P_bf,    // [M][64]
    const unsigned short* __restrict__ Wt_bf,   // [1024][2048]  (n-major)
    const unsigned short* __restrict__ Ut,      // [B][1024][64]
    const float* __restrict__ bias,             // [1024]
    float* __restrict__ out)                    // [M][1024]
{
  __shared__ unsigned short lds[65536];  // 128 KiB

  const int tid = threadIdx.x;
  const int w = tid >> 6, l = tid & 63;
  const int wm = w >> 2, wn = w & 3;       // 2 x 4 wave grid
  const int lrow = l & 15, lk = l >> 4;

  // XCD-aware bijective swizzle (nwg = 512, divisible by 8)
  const int orig = blockIdx.y * 4 + blockIdx.x;
  const int lid = (orig & 7) * 64 + (orig >> 3);
  const int nbase = (lid & 3) * 256;
  const int mbase = (lid >> 2) * 256;
  const int bidx = mbase >> 10;            // batch of this block's rows

  const int srow8 = w * 8 + (l >> 3);           // 0..63
  const int scol = ((l & 7) ^ (l >> 3)) << 3;   // pre-swizzled col chunk

  const int ck0 = ((lk)     ^ (lrow & 7)) << 3;
  const int ck1 = ((4 + lk) ^ (lrow & 7)) << 3;

#define STAGE_A(s, bsel, h) do {                                               \
    const unsigned short* p_; size_t str_;                                     \
    if ((s) < 16) { p_ = hid_bf + (s) * 64; str_ = 1024; }                     \
    else          { p_ = P_bf;              str_ = 64;   }                     \
    _Pragma("unroll")                                                          \
    for (int rd_ = 0; rd_ < 2; ++rd_)                                          \
      gll16(p_ + (size_t)(mbase + (h) * 128 + rd_ * 64 + srow8) * str_ + scol, \
            lds + (bsel) * 32768 + (h) * 8192 + rd_ * 4096 + w * 512);         \
  } while (0)

#define STAGE_B(s, bsel, h) do {                                               \
    const unsigned short* p_; size_t str_;                                     \
    if ((s) < 16) { p_ = Wt_bf + (s) * 64;               str_ = 2048; }        \
    else          { p_ = Ut + (size_t)bidx * HD * TT;    str_ = 64;   }        \
    _Pragma("unroll")                                                          \
    for (int rd_ = 0; rd_ < 2; ++rd_)                                          \
      gll16(p_ + (size_t)(nbase + (h) * 128 + rd_ * 64 + srow8) * str_ + scol, \
            lds + (bsel) * 32768 + 16384 + (h) * 8192 + rd_ * 4096 + w * 512); \
  } while (0)

#define PH_MID do { __builtin_amdgcn_s_setprio(1); } while (0)
#define PH_END do {                                                            \
    __builtin_amdgcn_s_setprio(0);                                             \
    __builtin_amdgcn_sched_barrier(0);                                         \
    __builtin_amdgcn_s_barrier();                                              \
  } while (0)

  f32x4 acc[8][4] = {};
  bf16x8 aR[4][2], bR[4][2];

  // prologue: A0,A1,B0,B1(tile0); B0,B1(tile1). vmcnt(4) -> tile0 landed.
  STAGE_A(0, 0, 0); STAGE_A(0, 0, 1);
  STAGE_B(0, 0, 0); STAGE_B(0, 0, 1);
  STAGE_B(1, 1, 0); STAGE_B(1, 1, 1);
  asm volatile("s_waitcnt vmcnt(4)" ::: "memory");
  __builtin_amdgcn_sched_barrier(0);
  __builtin_amdgcn_s_barrier();

#define TILE(tt, c, last) do {                                                 \
    const int sa_ = ((tt) + 1 > 16) ? 16 : (tt) + 1;                           \
    const int sb_ = ((tt) + 2 > 16) ? 16 : (tt) + 2;                           \
    const int abase_ = (c) * 32768 + wm * 8192 + lrow * 64;                    \
    const int bbase_ = (c) * 32768 + 16384 + (wn >> 1) * 8192                  \
                       + ((wn & 1) * 64 + lrow) * 64;                          \
    /* ---- P0: a[0..3], b[0..1]; stage A0(sa); MFMA m0-3 x n0-1 ---- */       \
    _Pragma("unroll")                                                          \
    for (int m_ = 0; m_ < 4; ++m_) {                                           \
      aR[m_][0] = *(const bf16x8*)(lds + abase_ + m_ * 1024 + ck0);            \
      aR[m_][1] = *(const bf16x8*)(lds + abase_ + m_ * 1024 + ck1);            \
    }                                                                          \
    _Pragma("unroll")                                                          \
    for (int n_ = 0; n_ < 2; ++n_) {                                           \
      bR[n_][0] = *(const bf16x8*)(lds + bbase_ + n_ * 1024 + ck0);            \
      bR[n_][1] = *(const bf16x8*)(lds + bbase_ + n_ * 1024 + ck1);            \
    }                                                                          \
    STAGE_A(sa_, 1 - (c), 0);                                                  \
    PH_MID;                                                                    \
    _Pragma("unroll")                                                          \
    for (int m_ = 0; m_ < 4; ++m_)                                             \
      _Pragma("unroll")                                                        \
      for (int n_ = 0; n_ < 2; ++n_) {                                         \
        acc[m_][n_] = __builtin_amdgcn_mfma_f32_16x16x32_bf16(                 \
            aR[m_][0], bR[n_][0], acc[m_][n_], 0, 0, 0);                       \
        acc[m_][n_] = __builtin_amdgcn_mfma_f32_16x16x32_bf16(                 \
            aR[m_][1], bR[n_][1], acc[m_][n_], 0, 0, 0);                       \
      }                                                                        \
    PH_END;                                                                    \
    /* ---- P1: b[2..3]; stage A1(sa); MFMA m0-3 x n2-3 ---- */                \
    _Pragma("unroll")                                                          \
    for (int n_ = 2; n_ < 4; ++n_) {                                           \
      bR[n_][0] = *(const bf16x8*)(lds + bbase_ + n_ * 1024 + ck0);            \
      bR[n_][1] = *(const bf16x8*)(lds + bbase_ + n_ * 1024 + ck1);            \
    }                                                                          \
    STAGE_A(sa_, 1 - (c), 1);                                                  \
    PH_MID;                                                                    \
    _Pragma("unroll")                                                          \
    for (int m_ = 0; m_ < 4; ++m_)                                             \
      _Pragma("unroll")                                                        \
      for (int n_ = 2; n_ < 4; ++n_) {                                         \
        acc[m_][n_] = __builtin_amdgcn_mfma_f32_16x16x32_bf16(                 \
            aR[m_][0], bR[n_][0], acc[m_][n_], 0, 0, 0);                       \
        acc[m_][n_] = __builtin_amdgcn_mfma_f32_16x16x32_bf16(                 \
            aR[m_][1], bR[n_][1], acc[m_][n_], 0, 0, 0);                       \
      }                                                                        \
    PH_END;                                                                    \
    /* ---- P2: a[4..7]; stage B0(sb); MFMA m4-7 x n0-1 ---- */                \
    _Pragma("unroll")                                                          \
    for (int m_ = 0; m_ < 4; ++m_) {                                           \
      aR[m_][0] = *(const bf16x8*)(lds + abase_ + (m_ + 4) * 1024 + ck0);      \
      aR[m_][1] = *(const bf16x8*)(lds + abase_ + (m_ + 4) * 1024 + ck1);      \
    }                                                                          \
    STAGE_B(sb_, (c), 0);                                                      \
    PH_MID;                                                                    \
    _Pragma("unroll")                                                          \
    for (int m_ = 0; m_ < 4; ++m_)                                             \
      _Pragma("unroll")                                                        \
      for (int n_ = 0; n_ < 2; ++n_) {                                         \
        acc[m_ + 4][n_] = __builtin_amdgcn_mfma_f32_16x16x32_bf16(             \
            aR[m_][0], bR[n_][0], acc[m_ + 4][n_], 0, 0, 0);                   \
        acc[m_ + 4][n_] = __builtin_amdgcn_mfma_f32_16x16x32_bf16(             \
            aR[m_][1], bR[n_][1], acc[m_ + 4][n_], 0, 0, 0);                   \
      }                                                                        \
    PH_END;                                                                    \
    /* ---- P3: stage B1(sb); MFMA m4-7 x n2-3; vmcnt ---- */                  \
    STAGE_B(sb_, (c), 1);                                                      \
    PH_MID;                                                                    \
    _Pragma("unroll")                                                          \
    for (int m_ = 0; m_ < 4; ++m_)                                             \
      _Pragma("unroll")                                                        \
      for (int n_ = 2; n_ < 4; ++n_) {                                         \
        acc[m_ + 4][n_] = __builtin_amdgcn_mfma_f32_16x16x32_bf16(             \
            aR[m_][0], bR[n_][0], acc[m_ + 4][n_], 0, 0, 0);                   \
        acc[m_ + 4][n_] = __builtin_amdgcn_mfma_f32_16x16x32_bf16(             \
            aR[m_][1], bR[n_][1], acc[m_ + 4][n_], 0, 0, 0);                   \
      }                                                                        \
    __builtin_amdgcn_s_setprio(0);                                             \
    if (last) { asm volatile("s_waitcnt vmcnt(0)" ::: "memory"); }             \
    else      { asm volatile("s_waitcnt vmcnt(4)" ::: "memory"); }             \
    __builtin_amdgcn_sched_barrier(0);                                         \
    __builtin_amdgcn_s_barrier();                                              \
  } while (0)

  for (int tt = 0; tt < 16; tt += 2) {
    TILE(tt, 0, false);
    TILE(tt + 1, 1, false);
  }
  TILE(16, 0, true);   // P x Ut[b] tile (dead stages keep vmcnt uniform)
#undef TILE
#undef PH_MID
#undef PH_END
#undef STAGE_A
#undef STAGE_B

  // epilogue: tanh + bias + bf16 residual (hid_bf L2/L3-warm)
#pragma unroll
  for (int m = 0; m < 8; ++m) {
    const int row = mbase + wm * 128 + m * 16 + lk * 4;
#pragma unroll
    for (int n = 0; n < 4; ++n) {
      const int col = nbase + wn * 64 + n * 16 + lrow;
      const float bv = bias[col];
#pragma unroll
      for (int j = 0; j < 4; ++j) {
        float x = acc[m][n][j] + bv;
        float xc = fminf(fmaxf(x, -15.f), 15.f);
        float e2 = __expf(2.f * xc);
        float th = (e2 - 1.f) / (e2 + 1.f);
        size_t oi = (size_t)(row + j) * HD + col;
        unsigned int u = ((unsigned int)hid_bf[oi]) << 16;
        out[oi] = th + __builtin_bit_cast(float, u);
      }
    }
  }
}

// ---------------------------------------------------------------- launch
extern "C" void kernel_launch(void* const* d_in, const int* in_sizes, int n_in,
                              void* d_out, int out_size, void* d_ws, size_t ws_size,
                              hipStream_t stream) {
  const float* tgt  = (const float*)d_in[0];  // (B,T,2H)
  const float* hid  = (const float*)d_in[1];  // (B,S,2H)
  const float* W    = (const float*)d_in[2];  // (4H,2H)
  const float* bias = (const float*)d_in[3];  // (2H,)
  float* out = (float*)d_out;

  char* ws = (char*)d_ws;
  unsigned short* hid_bf = (unsigned short*)(ws);                //  64 MiB
  unsigned short* tgt_bf = (unsigned short*)(ws + 67108864);     //   4 MiB
  unsigned short* Wt_bf  = (unsigned short*)(ws + 71303168);     //   4 MiB
  unsigned short* P_bf   = (unsigned short*)(ws + 75497472);     //   4 MiB
  unsigned short* Ut     = (unsigned short*)(ws + 79691776);     //   4 MiB

  cvt_bf16_kernel<<<2048, 256, 0, stream>>>(hid, hid_bf, (MM * HD) / 4);
  cvt_bf16_kernel<<<512, 256, 0, stream>>>(tgt, tgt_bf, (BB * TT * HD) / 4);
  tcvt_kernel<<<dim3(HD / 32, FF / 32), dim3(32, 8), 0, stream>>>(W, Wt_bf, FF, HD);
  u_kernel<<<dim3(HD / 64, BB), 256, 0, stream>>>(tgt_bf, Wt_bf, Ut);
  attn_kernel<<<dim3(SS / 64, BB), 256, 0, stream>>>(hid_bf, tgt_bf, P_bf);
  gemm_kernel<<<dim3(HD / 128 / 2, MM / 256), 512, 0, stream>>>(hid_bf, P_bf, Wt_bf, Ut, bias, out);
}

// Round 12
// 210.398 us; speedup vs baseline: 1.0429x; 1.0334x over previous
//
#include <hip/hip_runtime.h>
#include <hip/hip_bf16.h>

// Problem constants
#define BB 32
#define SS 1024
#define TT 64
#define HD 1024   // 2H
#define FF 2048   // 4H
#define MM (BB*SS) // 32768

typedef __attribute__((ext_vector_type(4))) float f32x4;
typedef __attribute__((ext_vector_type(8))) short bf16x8;
typedef __attribute__((ext_vector_type(8))) unsigned short u16x8;

__device__ __forceinline__ unsigned short f2bf(float f) {
  __hip_bfloat16 h = __float2bfloat16(f);
  return __builtin_bit_cast(unsigned short, h);
}

__device__ __forceinline__ void gll16(const void* g, void* l) {
  __builtin_amdgcn_global_load_lds(
      (const __attribute__((address_space(1))) void*)g,
      (__attribute__((address_space(3))) void*)l, 16, 0, 0);
}

// ---------------------------------------------------------------- converts
__global__ void cvt_bf16_kernel(const float* __restrict__ x,
                                unsigned short* __restrict__ y, int n4) {
  int stride = gridDim.x * blockDim.x;
  for (int i = blockIdx.x * blockDim.x + threadIdx.x; i < n4; i += stride) {
    float4 v = reinterpret_cast<const float4*>(x)[i];
    ushort4 o;
    o.x = f2bf(v.x); o.y = f2bf(v.y); o.z = f2bf(v.z); o.w = f2bf(v.w);
    reinterpret_cast<ushort4*>(y)[i] = o;
  }
}

// transpose+convert: in fp32 [R][C] -> out bf16 [C][R]   (W: 2048x1024 -> 1024x2048)
__global__ void tcvt_kernel(const float* __restrict__ in,
                            unsigned short* __restrict__ out, int R, int C) {
  __shared__ float tile[32][33];
  const int c0 = blockIdx.x * 32, r0 = blockIdx.y * 32;
  const int tx = threadIdx.x, ty = threadIdx.y; // (32, 8)
#pragma unroll
  for (int j = 0; j < 4; ++j)
    tile[ty + j * 8][tx] = in[(size_t)(r0 + ty + j * 8) * C + c0 + tx];
  __syncthreads();
#pragma unroll
  for (int j = 0; j < 4; ++j)
    out[(size_t)(c0 + ty + j * 8) * R + r0 + tx] = f2bf(tile[tx][ty + j * 8]);
}

// ---------------------------------------------------------------- U = tgt @ W2
// Ut[b][d][t] bf16 (transposed) so the main gemm stages it as stride-64 B-tile.
__global__ __launch_bounds__(256) void u_kernel(
    const unsigned short* __restrict__ tgt_bf,  // [B][T][1024]
    const unsigned short* __restrict__ Wt_bf,   // [1024 d][2048 f]
    unsigned short* __restrict__ Ut)            // [B][1024 d][64 t]
{
  const int tid = threadIdx.x;
  const int w = tid >> 6, l = tid & 63;
  const int lrow = l & 15, lk = l >> 4;
  const int nb = blockIdx.x * 64;   // d base
  const int b = blockIdx.y;

  const unsigned short* ap = tgt_bf + (size_t)b * TT * HD
                             + (size_t)(w * 16 + lrow) * HD + lk * 8;
  const unsigned short* wp = Wt_bf + (size_t)(nb + lrow) * FF + 1024 + lk * 8;

  f32x4 acc[4] = {};
  for (int kt = 0; kt < 32; ++kt) {
    const int kk = kt * 32;
    bf16x8 a = *reinterpret_cast<const bf16x8*>(ap + kk);
#pragma unroll
    for (int ct = 0; ct < 4; ++ct) {
      bf16x8 bb = *reinterpret_cast<const bf16x8*>(wp + (size_t)ct * 16 * FF + kk);
      acc[ct] = __builtin_amdgcn_mfma_f32_16x16x32_bf16(a, bb, acc[ct], 0, 0, 0);
    }
  }
  unsigned short* up = Ut + (size_t)b * HD * TT;
#pragma unroll
  for (int ct = 0; ct < 4; ++ct)
#pragma unroll
    for (int j = 0; j < 4; ++j)
      up[(size_t)(nb + ct * 16 + lrow) * TT + (w * 16 + lk * 4 + j)] = f2bf(acc[ct][j]);
}

// ---------------------------------------------------------------- attention
// R12: R9's fused-convert barrier-free QK^T, with K SPLIT ACROSS WAVE PAIRS.
// 512 threads = 4 row-groups x 2 K-halves. Each wave: 16 iters of
// {fp32 load -> cvt -> hid_bf store -> 4 MFMA} over its K-half (every hid
// element read/written exactly once). Pair-reduce partial accs via padded
// LDS, even wave does softmax + P store. Waves/CU: 8 -> 16 (TLP doubled).
__global__ __launch_bounds__(512) void attn_kernel(
    const float* __restrict__ hid_f32,           // [B][S][D] fp32
    unsigned short* __restrict__ hid_bf,         // out: [B][S][D] bf16
    const unsigned short* __restrict__ tgt_bf,   // [B][T][D]
    unsigned short* __restrict__ P_bf)           // out: [M][64]
{
  __shared__ float red[4][64][20];  // 20 KB; 20 floats = 80 B (16B-aligned rows)

  const int tid = threadIdx.x;
  const int w = tid >> 6, l = tid & 63;
  const int pair = w >> 1, half = w & 1;
  const int lrow = l & 15, lk = l >> 4;
  const int b = blockIdx.y;
  const int sbase = blockIdx.x * 64;
  const size_t hbase = ((size_t)b * SS + sbase) * HD;

  const int qrow = pair * 16 + lrow;
  const float* qp = hid_f32 + hbase + (size_t)qrow * HD + lk * 8;
  unsigned short* qbf = hid_bf + hbase + (size_t)qrow * HD + lk * 8;
  const unsigned short* kp = tgt_bf + (size_t)b * TT * HD + (size_t)lrow * HD + lk * 8;

  f32x4 accs[4] = {};
  const int ktend = half * 16 + 16;
#pragma unroll 2
  for (int kt = half * 16; kt < ktend; ++kt) {
    const int kk = kt * 32;
    float4 f0 = *reinterpret_cast<const float4*>(qp + kk);
    float4 f1 = *reinterpret_cast<const float4*>(qp + kk + 4);
    bf16x8 a;
    a[0] = (short)f2bf(f0.x); a[1] = (short)f2bf(f0.y);
    a[2] = (short)f2bf(f0.z); a[3] = (short)f2bf(f0.w);
    a[4] = (short)f2bf(f1.x); a[5] = (short)f2bf(f1.y);
    a[6] = (short)f2bf(f1.z); a[7] = (short)f2bf(f1.w);
    *reinterpret_cast<bf16x8*>(qbf + kk) = a;   // hid_bf side output
#pragma unroll
    for (int ct = 0; ct < 4; ++ct) {
      bf16x8 bb = *reinterpret_cast<const bf16x8*>(kp + (size_t)ct * 16 * HD + kk);
      accs[ct] = __builtin_amdgcn_mfma_f32_16x16x32_bf16(a, bb, accs[ct], 0, 0, 0);
    }
  }

  if (half == 1) {
#pragma unroll
    for (int ct = 0; ct < 4; ++ct)
      *reinterpret_cast<f32x4*>(&red[pair][l][ct * 4]) = accs[ct];
  }
  __syncthreads();
  if (half == 0) {
#pragma unroll
    for (int ct = 0; ct < 4; ++ct)
      accs[ct] += *reinterpret_cast<const f32x4*>(&red[pair][l][ct * 4]);

    // softmax over t (lane holds q-rows lk*4+j, t-cols ct*16+lrow)
    float p[4][4];
#pragma unroll
    for (int j = 0; j < 4; ++j) {
      float mx = fmaxf(fmaxf(accs[0][j], accs[1][j]), fmaxf(accs[2][j], accs[3][j]));
#pragma unroll
      for (int d = 1; d < 16; d <<= 1) mx = fmaxf(mx, __shfl_xor(mx, d, 64));
      float sum = 0.f;
#pragma unroll
      for (int ct = 0; ct < 4; ++ct) { p[ct][j] = __expf(accs[ct][j] - mx); sum += p[ct][j]; }
#pragma unroll
      for (int d = 1; d < 16; d <<= 1) sum += __shfl_xor(sum, d, 64);
      float inv = 1.f / sum;
#pragma unroll
      for (int ct = 0; ct < 4; ++ct) p[ct][j] *= inv;
    }
#pragma unroll
    for (int j = 0; j < 4; ++j) {
      const size_t prow = ((size_t)b * SS + sbase + pair * 16 + lk * 4 + j) * TT;
#pragma unroll
      for (int ct = 0; ct < 4; ++ct)
        P_bf[prow + ct * 16 + lrow] = f2bf(p[ct][j]);
    }
  }
}

// ---------------------------------------------------------------- transform GEMM
// out = tanh(hid.W1 + P.U + b) + hid.  K = 1024 (hid x W1) + 64 (P x Ut[b]).
// R9 measured: 104.5us, 0 conflicts. Unchanged.

__global__ __launch_bounds__(512) void gemm_kernel(
    const unsigned short* __restrict__ hid_bf,  // [M][1024]
    const unsigned short* __restrict__ P_bf,    // [M][64]
    const unsigned short* __restrict__ Wt_bf,   // [1024][2048]  (n-major)
    const unsigned short* __restrict__ Ut,      // [B][1024][64]
    const float* __restrict__ bias,             // [1024]
    float* __restrict__ out)                    // [M][1024]
{
  __shared__ unsigned short lds[65536];  // 128 KiB

  const int tid = threadIdx.x;
  const int w = tid >> 6, l = tid & 63;
  const int wm = w >> 2, wn = w & 3;       // 2 x 4 wave grid
  const int lrow = l & 15, lk = l >> 4;

  // XCD-aware bijective swizzle (nwg = 512, divisible by 8)
  const int orig = blockIdx.y * 4 + blockIdx.x;
  const int lid = (orig & 7) * 64 + (orig >> 3);
  const int nbase = (lid & 3) * 256;
  const int mbase = (lid >> 2) * 256;
  const int bidx = mbase >> 10;            // batch of this block's rows

  const int srow8 = w * 8 + (l >> 3);           // 0..63
  const int scol = ((l & 7) ^ (l >> 3)) << 3;   // pre-swizzled col chunk

  const int ck0 = ((lk)     ^ (lrow & 7)) << 3;
  const int ck1 = ((4 + lk) ^ (lrow & 7)) << 3;

#define STAGE_A(s, bsel, h) do {                                               \
    const unsigned short* p_; size_t str_;                                     \
    if ((s) < 16) { p_ = hid_bf + (s) * 64; str_ = 1024; }                     \
    else          { p_ = P_bf;              str_ = 64;   }                     \
    _Pragma("unroll")                                                          \
    for (int rd_ = 0; rd_ < 2; ++rd_)                                          \
      gll16(p_ + (size_t)(mbase + (h) * 128 + rd_ * 64 + srow8) * str_ + scol, \
            lds + (bsel) * 32768 + (h) * 8192 + rd_ * 4096 + w * 512);         \
  } while (0)

#define STAGE_B(s, bsel, h) do {                                               \
    const unsigned short* p_; size_t str_;                                     \
    if ((s) < 16) { p_ = Wt_bf + (s) * 64;               str_ = 2048; }        \
    else          { p_ = Ut + (size_t)bidx * HD * TT;    str_ = 64;   }        \
    _Pragma("unroll")                                                          \
    for (int rd_ = 0; rd_ < 2; ++rd_)                                          \
      gll16(p_ + (size_t)(nbase + (h) * 128 + rd_ * 64 + srow8) * str_ + scol, \
            lds + (bsel) * 32768 + 16384 + (h) * 8192 + rd_ * 4096 + w * 512); \
  } while (0)

#define PH_MID do { __builtin_amdgcn_s_setprio(1); } while (0)
#define PH_END do {                                                            \
    __builtin_amdgcn_s_setprio(0);                                             \
    __builtin_amdgcn_sched_barrier(0);                                         \
    __builtin_amdgcn_s_barrier();                                              \
  } while (0)

  f32x4 acc[8][4] = {};
  bf16x8 aR[4][2], bR[4][2];

  // prologue: A0,A1,B0,B1(tile0); B0,B1(tile1). vmcnt(4) -> tile0 landed.
  STAGE_A(0, 0, 0); STAGE_A(0, 0, 1);
  STAGE_B(0, 0, 0); STAGE_B(0, 0, 1);
  STAGE_B(1, 1, 0); STAGE_B(1, 1, 1);
  asm volatile("s_waitcnt vmcnt(4)" ::: "memory");
  __builtin_amdgcn_sched_barrier(0);
  __builtin_amdgcn_s_barrier();

#define TILE(tt, c, last) do {                                                 \
    const int sa_ = ((tt) + 1 > 16) ? 16 : (tt) + 1;                           \
    const int sb_ = ((tt) + 2 > 16) ? 16 : (tt) + 2;                           \
    const int abase_ = (c) * 32768 + wm * 8192 + lrow * 64;                    \
    const int bbase_ = (c) * 32768 + 16384 + (wn >> 1) * 8192                  \
                       + ((wn & 1) * 64 + lrow) * 64;                          \
    /* ---- P0: a[0..3], b[0..1]; stage A0(sa); MFMA m0-3 x n0-1 ---- */       \
    _Pragma("unroll")                                                          \
    for (int m_ = 0; m_ < 4; ++m_) {                                           \
      aR[m_][0] = *(const bf16x8*)(lds + abase_ + m_ * 1024 + ck0);            \
      aR[m_][1] = *(const bf16x8*)(lds + abase_ + m_ * 1024 + ck1);            \
    }                                                                          \
    _Pragma("unroll")                                                          \
    for (int n_ = 0; n_ < 2; ++n_) {                                           \
      bR[n_][0] = *(const bf16x8*)(lds + bbase_ + n_ * 1024 + ck0);            \
      bR[n_][1] = *(const bf16x8*)(lds + bbase_ + n_ * 1024 + ck1);            \
    }                                                                          \
    STAGE_A(sa_, 1 - (c), 0);                                                  \
    PH_MID;                                                                    \
    _Pragma("unroll")                                                          \
    for (int m_ = 0; m_ < 4; ++m_)                                             \
      _Pragma("unroll")                                                        \
      for (int n_ = 0; n_ < 2; ++n_) {                                         \
        acc[m_][n_] = __builtin_amdgcn_mfma_f32_16x16x32_bf16(                 \
            aR[m_][0], bR[n_][0], acc[m_][n_], 0, 0, 0);                       \
        acc[m_][n_] = __builtin_amdgcn_mfma_f32_16x16x32_bf16(                 \
            aR[m_][1], bR[n_][1], acc[m_][n_], 0, 0, 0);                       \
      }                                                                        \
    PH_END;                                                                    \
    /* ---- P1: b[2..3]; stage A1(sa); MFMA m0-3 x n2-3 ---- */                \
    _Pragma("unroll")                                                          \
    for (int n_ = 2; n_ < 4; ++n_) {                                           \
      bR[n_][0] = *(const bf16x8*)(lds + bbase_ + n_ * 1024 + ck0);            \
      bR[n_][1] = *(const bf16x8*)(lds + bbase_ + n_ * 1024 + ck1);            \
    }                                                                          \
    STAGE_A(sa_, 1 - (c), 1);                                                  \
    PH_MID;                                                                    \
    _Pragma("unroll")                                                          \
    for (int m_ = 0; m_ < 4; ++m_)                                             \
      _Pragma("unroll")                                                        \
      for (int n_ = 2; n_ < 4; ++n_) {                                         \
        acc[m_][n_] = __builtin_amdgcn_mfma_f32_16x16x32_bf16(                 \
            aR[m_][0], bR[n_][0], acc[m_][n_], 0, 0, 0);                       \
        acc[m_][n_] = __builtin_amdgcn_mfma_f32_16x16x32_bf16(                 \
            aR[m_][1], bR[n_][1], acc[m_][n_], 0, 0, 0);                       \
      }                                                                        \
    PH_END;                                                                    \
    /* ---- P2: a[4..7]; stage B0(sb); MFMA m4-7 x n0-1 ---- */                \
    _Pragma("unroll")                                                          \
    for (int m_ = 0; m_ < 4; ++m_) {                                           \
      aR[m_][0] = *(const bf16x8*)(lds + abase_ + (m_ + 4) * 1024 + ck0);      \
      aR[m_][1] = *(const bf16x8*)(lds + abase_ + (m_ + 4) * 1024 + ck1);      \
    }                                                                          \
    STAGE_B(sb_, (c), 0);                                                      \
    PH_MID;                                                                    \
    _Pragma("unroll")                                                          \
    for (int m_ = 0; m_ < 4; ++m_)                                             \
      _Pragma("unroll")                                                        \
      for (int n_ = 0; n_ < 2; ++n_) {                                         \
        acc[m_ + 4][n_] = __builtin_amdgcn_mfma_f32_16x16x32_bf16(             \
            aR[m_][0], bR[n_][0], acc[m_ + 4][n_], 0, 0, 0);                   \
        acc[m_ + 4][n_] = __builtin_amdgcn_mfma_f32_16x16x32_bf16(             \
            aR[m_][1], bR[n_][1], acc[m_ + 4][n_], 0, 0, 0);                   \
      }                                                                        \
    PH_END;                                                                    \
    /* ---- P3: stage B1(sb); MFMA m4-7 x n2-3; vmcnt ---- */                  \
    STAGE_B(sb_, (c), 1);                                                      \
    PH_MID;                                                                    \
    _Pragma("unroll")                                                          \
    for (int m_ = 0; m_ < 4; ++m_)                                             \
      _Pragma("unroll")                                                        \
      for (int n_ = 2; n_ < 4; ++n_) {                                         \
        acc[m_ + 4][n_] = __builtin_amdgcn_mfma_f32_16x16x32_bf16(             \
            aR[m_][0], bR[n_][0], acc[m_ + 4][n_], 0, 0, 0);                   \
        acc[m_ + 4][n_] = __builtin_amdgcn_mfma_f32_16x16x32_bf16(             \
            aR[m_][1], bR[n_][1], acc[m_ + 4][n_], 0, 0, 0);                   \
      }                                                                        \
    __builtin_amdgcn_s_setprio(0);                                             \
    if (last) { asm volatile("s_waitcnt vmcnt(0)" ::: "memory"); }             \
    else      { asm volatile("s_waitcnt vmcnt(4)" ::: "memory"); }             \
    __builtin_amdgcn_sched_barrier(0);                                         \
    __builtin_amdgcn_s_barrier();                                              \
  } while (0)

  for (int tt = 0; tt < 16; tt += 2) {
    TILE(tt, 0, false);
    TILE(tt + 1, 1, false);
  }
  TILE(16, 0, true);   // P x Ut[b] tile (dead stages keep vmcnt uniform)
#undef TILE
#undef PH_MID
#undef PH_END
#undef STAGE_A
#undef STAGE_B

  // epilogue: tanh + bias + bf16 residual (hid_bf L2/L3-warm)
#pragma unroll
  for (int m = 0; m < 8; ++m) {
    const int row = mbase + wm * 128 + m * 16 + lk * 4;
#pragma unroll
    for (int n = 0; n < 4; ++n) {
      const int col = nbase + wn * 64 + n * 16 + lrow;
      const float bv = bias[col];
#pragma unroll
      for (int j = 0; j < 4; ++j) {
        float x = acc[m][n][j] + bv;
        float xc = fminf(fmaxf(x, -15.f), 15.f);
        float e2 = __expf(2.f * xc);
        float th = (e2 - 1.f) / (e2 + 1.f);
        size_t oi = (size_t)(row + j) * HD + col;
        unsigned int u = ((unsigned int)hid_bf[oi]) << 16;
        out[oi] = th + __builtin_bit_cast(float, u);
      }
    }
  }
}

// ---------------------------------------------------------------- launch
extern "C" void kernel_launch(void* const* d_in, const int* in_sizes, int n_in,
                              void* d_out, int out_size, void* d_ws, size_t ws_size,
                              hipStream_t stream) {
  const float* tgt  = (const float*)d_in[0];  // (B,T,2H)
  const float* hid  = (const float*)d_in[1];  // (B,S,2H)
  const float* W    = (const float*)d_in[2];  // (4H,2H)
  const float* bias = (const float*)d_in[3];  // (2H,)
  float* out = (float*)d_out;

  char* ws = (char*)d_ws;
  unsigned short* hid_bf = (unsigned short*)(ws);                //  64 MiB
  unsigned short* tgt_bf = (unsigned short*)(ws + 67108864);     //   4 MiB
  unsigned short* Wt_bf  = (unsigned short*)(ws + 71303168);     //   4 MiB
  unsigned short* P_bf   = (unsigned short*)(ws + 75497472);     //   4 MiB
  unsigned short* Ut     = (unsigned short*)(ws + 79691776);     //   4 MiB

  cvt_bf16_kernel<<<512, 256, 0, stream>>>(tgt, tgt_bf, (BB * TT * HD) / 4);
  tcvt_kernel<<<dim3(HD / 32, FF / 32), dim3(32, 8), 0, stream>>>(W, Wt_bf, FF, HD);
  u_kernel<<<dim3(HD / 64, BB), 256, 0, stream>>>(tgt_bf, Wt_bf, Ut);
  attn_kernel<<<dim3(SS / 64, BB), 512, 0, stream>>>(hid, hid_bf, tgt_bf, P_bf);
  gemm_kernel<<<dim3(HD / 128 / 2, MM / 256), 512, 0, stream>>>(hid_bf, P_bf, Wt_bf, Ut, bias, out);
}